// Round 13
// baseline (753.807 us; speedup 1.0000x reference)
//
#include <hip/hip_runtime.h>
#include <hip/hip_bf16.h>

// Problem constants (from reference)
#define NTOK 8192      // B*T = 4*2048
#define DIM 1024
#define NEXP 8
#define HID 2816
#define NPAIR (NTOK * 2)   // TOP_K = 2

#define BK 64
#define BM 128                 // shared m-tile worklist for both gemms
#define G1_BN 64               // h-cols per block (fused w1+w3)
#define G2_BN 128
#define KSPLIT 2               // gemm2 split-K
#define MAXT 136               // >= ceil(NPAIR/128) + NEXP - 1 = 135
#define G1_NSL (HID / G1_BN)   // 44
#define G2_NSL (DIM / G2_BN)   // 8
#define G1_NWG (MAXT * G1_NSL)           // 5984 (div by 8)
#define G2_NWG (MAXT * G2_NSL * KSPLIT)  // 2176 (div by 8)
#define NK1 (DIM / BK)         // 16
#define NK2 (HID / BK)         // 44 (22 per K-half)

typedef unsigned short u16;
typedef __attribute__((ext_vector_type(8))) short short8;
typedef __attribute__((ext_vector_type(4))) float f32x4;

// T2 swizzled LDS read: logical (row, kc-u16) -> 16B-slot XOR by row&7.
// Plain C++ load: compiler emits fine-grained lgkmcnt interleaved with MFMAs.
#define LDSWZ(arr, r, kc) \
  (*(const short8*)&arr[(r) * BK + ((kc) ^ (((r) & 7) << 3))])

static __device__ __forceinline__ u16 f2bf(float f) {
  union { float f; unsigned u; } v; v.f = f;
  unsigned r = v.u + 0x7fff + ((v.u >> 16) & 1);  // RTNE
  return (u16)(r >> 16);
}

// async global->LDS, 16B/lane; LDS dest = wave-uniform base + lane*16B
static __device__ __forceinline__ void gload16(const void* g, void* l) {
  __builtin_amdgcn_global_load_lds(
      (const __attribute__((address_space(1))) unsigned*)(g),
      (__attribute__((address_space(3))) unsigned*)(l), 16, 0, 0);
}

// ---------------- fp32 -> bf16 conversion of the 3 weight tensors ----------
__global__ void cvt3_kernel(const float* __restrict__ s0, const float* __restrict__ s1,
                            const float* __restrict__ s2, u16* __restrict__ d0,
                            u16* __restrict__ d1, u16* __restrict__ d2, int n) {
  int stride = gridDim.x * blockDim.x;
  for (int i = blockIdx.x * blockDim.x + threadIdx.x; i * 4 < n; i += stride) {
    float4 a = *reinterpret_cast<const float4*>(s0 + (size_t)i * 4);
    float4 b = *reinterpret_cast<const float4*>(s1 + (size_t)i * 4);
    float4 c = *reinterpret_cast<const float4*>(s2 + (size_t)i * 4);
    ushort4 oa, ob, oc;
    oa.x = f2bf(a.x); oa.y = f2bf(a.y); oa.z = f2bf(a.z); oa.w = f2bf(a.w);
    ob.x = f2bf(b.x); ob.y = f2bf(b.y); ob.z = f2bf(b.z); ob.w = f2bf(b.w);
    oc.x = f2bf(c.x); oc.y = f2bf(c.y); oc.z = f2bf(c.z); oc.w = f2bf(c.w);
    *reinterpret_cast<ushort4*>(d0 + (size_t)i * 4) = oa;
    *reinterpret_cast<ushort4*>(d1 + (size_t)i * 4) = ob;
    *reinterpret_cast<ushort4*>(d2 + (size_t)i * 4) = oc;
  }
}

// ---------------- router (fused with x -> bf16 conversion) ------------------
__global__ void router_kernel(const float* __restrict__ x, const float* __restrict__ gw,
                              int* __restrict__ cnt, int* __restrict__ tok_e,
                              float* __restrict__ tok_w, u16* __restrict__ xb) {
  int t = blockIdx.x;
  int lane = threadIdx.x;  // 64 = 1 wave
  const float* xr = x + (size_t)t * DIM;
  u16* xbr = xb + (size_t)t * DIM;
  float acc[NEXP];
#pragma unroll
  for (int e = 0; e < NEXP; ++e) acc[e] = 0.f;
  for (int d = lane * 4; d < DIM; d += 256) {
    float4 v = *reinterpret_cast<const float4*>(xr + d);
    ushort4 o;
    o.x = f2bf(v.x); o.y = f2bf(v.y); o.z = f2bf(v.z); o.w = f2bf(v.w);
    *reinterpret_cast<ushort4*>(xbr + d) = o;
#pragma unroll
    for (int e = 0; e < NEXP; ++e) {
      const float* g = gw + e * DIM + d;
      acc[e] += v.x * g[0] + v.y * g[1] + v.z * g[2] + v.w * g[3];
    }
  }
#pragma unroll
  for (int e = 0; e < NEXP; ++e) {
#pragma unroll
    for (int o = 32; o > 0; o >>= 1) acc[e] += __shfl_xor(acc[e], o);
  }
  if (lane == 0) {
    float m = acc[0];
#pragma unroll
    for (int e = 1; e < NEXP; ++e) m = fmaxf(m, acc[e]);
    float p[NEXP];
#pragma unroll
    for (int e = 0; e < NEXP; ++e) p[e] = __expf(acc[e] - m);
    int e0 = 0; float b0 = p[0];
#pragma unroll
    for (int e = 1; e < NEXP; ++e) if (p[e] > b0) { e0 = e; b0 = p[e]; }
    int e1 = -1; float b1 = -1.f;
#pragma unroll
    for (int e = 0; e < NEXP; ++e) if (e != e0 && p[e] > b1) { e1 = e; b1 = p[e]; }
    float inv = 1.f / (b0 + b1);
    atomicAdd(&cnt[e0], 1);
    atomicAdd(&cnt[e1], 1);
    tok_e[2 * t] = e0; tok_e[2 * t + 1] = e1;
    tok_w[2 * t] = b0 * inv; tok_w[2 * t + 1] = b1 * inv;
  }
}

// ------- prefix + flat m-tile worklist (BM=128, shared by both gemms) ------
__global__ void prefix_kernel(const int* __restrict__ cnt, int* __restrict__ off,
                              int* __restrict__ fill,
                              int* __restrict__ tle, int* __restrict__ tlmb,
                              int* __restrict__ ntiles) {
  if (threadIdx.x == 0 && blockIdx.x == 0) {
    int s = 0, nt = 0;
    for (int e = 0; e < NEXP; ++e) {
      off[e] = s;
      for (int mb = 0; mb < cnt[e]; mb += BM) { tle[nt] = e; tlmb[nt] = s + mb; ++nt; }
      s += cnt[e]; fill[e] = 0;
    }
    off[NEXP] = s;
    *ntiles = nt;
  }
}

// ---------------- scatter --------------------------------------------------
__global__ void scatter_kernel(const int* __restrict__ tok_e, const float* __restrict__ tok_w,
                               const int* __restrict__ off, int* __restrict__ fill,
                               int* __restrict__ pair_tok, float* __restrict__ pair_w) {
  int t = blockIdx.x * blockDim.x + threadIdx.x;
  if (t >= NTOK) return;
#pragma unroll
  for (int k = 0; k < 2; ++k) {
    int e = tok_e[2 * t + k];
    int slot = off[e] + atomicAdd(&fill[e], 1);
    pair_tok[slot] = t;
    pair_w[slot] = tok_w[2 * t + k];
  }
}

// ---------------- GEMM1: h = silu(x @ w1^T) * (x @ w3^T) -------------------
// m97 structure: 128x64 fused tile, 4 waves (2x2), single-buffer 32KB LDS,
// 2-sync K-loop, multi-block/CU implicit overlap. T2 swizzle. A-major XCD.
__launch_bounds__(256, 4)
__global__ void gemm1_kernel(const u16* __restrict__ xb, const u16* __restrict__ w1b,
                             const u16* __restrict__ w3b, u16* __restrict__ hbuf,
                             const int* __restrict__ off, const int* __restrict__ pair_tok,
                             const int* __restrict__ tile_e, const int* __restrict__ tile_mb,
                             const int* __restrict__ ntiles) {
  int bid = blockIdx.x;
  int swz = (bid & 7) * (G1_NWG / 8) + (bid >> 3);   // bijective: G1_NWG%8==0
  int ti = swz / G1_NSL;                              // A-major: 44 slices share A in L2
  int n0 = (swz % G1_NSL) * G1_BN;
  if (ti >= *ntiles) return;
  int e = tile_e[ti];
  int mbase = tile_mb[ti];
  int nrows = off[e + 1] - mbase; if (nrows > BM) nrows = BM;

  __shared__ u16 As[BM * BK];      // 16KB, single buffer
  __shared__ u16 B1s[G1_BN * BK];  // 8KB
  __shared__ u16 B3s[G1_BN * BK];  // 8KB

  int tid = threadIdx.x;
  int lane = tid & 63;
  int wid = tid >> 6;
  int wr = wid >> 1, wc = wid & 1;     // 2(M) x 2(N); wave out 64 x 32 (x2 mats)
  int lrow = lane & 15, kgrp = lane >> 4;

  int srow = tid >> 3;                              // 0..31
  int scol = ((tid & 7) ^ (srow & 7)) * 8;          // rule #21: swz on source
  const u16* pA[4]; const u16* pB1[2]; const u16* pB3[2];
  const u16* w1base = w1b + (size_t)e * HID * DIM;
  const u16* w3base = w3b + (size_t)e * HID * DIM;
#pragma unroll
  for (int j = 0; j < 4; ++j) {
    int r = j * 32 + srow;
    int ra = r < nrows ? r : nrows - 1;             // clamp ragged tile
    pA[j] = xb + (size_t)pair_tok[mbase + ra] * DIM + scol;
  }
#pragma unroll
  for (int j = 0; j < 2; ++j) {
    int r = j * 32 + srow;
    pB1[j] = w1base + (size_t)(n0 + r) * DIM + scol;
    pB3[j] = w3base + (size_t)(n0 + r) * DIM + scol;
  }

  f32x4 acc1[4][2], acc3[4][2];
#pragma unroll
  for (int m = 0; m < 4; ++m)
#pragma unroll
    for (int n = 0; n < 2; ++n) { acc1[m][n] = (f32x4)0.f; acc3[m][n] = (f32x4)0.f; }

#pragma unroll 1
  for (int kt = 0; kt < NK1; ++kt) {
    int kk = kt * BK;
#pragma unroll
    for (int j = 0; j < 4; ++j)
      gload16(pA[j] + kk, &As[(j * 32 + wid * 8) * BK]);
#pragma unroll
    for (int j = 0; j < 2; ++j) {
      gload16(pB1[j] + kk, &B1s[(j * 32 + wid * 8) * BK]);
      gload16(pB3[j] + kk, &B3s[(j * 32 + wid * 8) * BK]);
    }
    __syncthreads();   // drains vmcnt(0): whole tile in LDS
#pragma unroll
    for (int ks = 0; ks < 2; ++ks) {
      int kc = ks * 32 + kgrp * 8;
      short8 a[4], b1[2], b3[2];
#pragma unroll
      for (int m = 0; m < 4; ++m) a[m] = LDSWZ(As, wr * 64 + m * 16 + lrow, kc);
#pragma unroll
      for (int n = 0; n < 2; ++n) {
        b1[n] = LDSWZ(B1s, wc * 32 + n * 16 + lrow, kc);
        b3[n] = LDSWZ(B3s, wc * 32 + n * 16 + lrow, kc);
      }
#pragma unroll
      for (int m = 0; m < 4; ++m)
#pragma unroll
        for (int n = 0; n < 2; ++n) {
          acc1[m][n] = __builtin_amdgcn_mfma_f32_16x16x32_bf16(a[m], b1[n], acc1[m][n], 0, 0, 0);
          acc3[m][n] = __builtin_amdgcn_mfma_f32_16x16x32_bf16(a[m], b3[n], acc3[m][n], 0, 0, 0);
        }
    }
    __syncthreads();   // all reads complete -> next stage may overwrite
  }

  // epilogue: silu(acc1)*acc3 -> bf16 h
#pragma unroll
  for (int m = 0; m < 4; ++m)
#pragma unroll
    for (int n = 0; n < 2; ++n)
#pragma unroll
      for (int r = 0; r < 4; ++r) {
        int rowt = wr * 64 + m * 16 + kgrp * 4 + r;   // C/D: row=(lane>>4)*4+r, col=lane&15
        if (rowt < nrows) {
          float v1 = acc1[m][n][r], v3 = acc3[m][n][r];
          float hv = v1 / (1.f + __expf(-v1)) * v3;
          hbuf[(size_t)(mbase + rowt) * HID + (n0 + wc * 32 + n * 16 + lrow)] = f2bf(hv);
        }
      }
}

// ---------------- GEMM2: out[tok] += (h @ w2^T) * pair_w -------------------
// m97 structure: 128x128 tile, 4 waves, 32KB LDS; split-K=2; A-major XCD;
// epilogue atomicAdds scaled partials directly into out (no y2/combine).
__launch_bounds__(256, 3)
__global__ void gemm2_kernel(const u16* __restrict__ hbuf, const u16* __restrict__ w2b,
                             float* __restrict__ out, const int* __restrict__ off,
                             const int* __restrict__ pair_tok, const float* __restrict__ pair_w,
                             const int* __restrict__ tile_e, const int* __restrict__ tile_mb,
                             const int* __restrict__ ntiles) {
  int bid = blockIdx.x;
  int swz = (bid & 7) * (G2_NWG / 8) + (bid >> 3);   // bijective: G2_NWG%8==0
  int ti = swz / (G2_NSL * KSPLIT);                  // A-major: 16 blocks share A-tile
  int rem = swz % (G2_NSL * KSPLIT);
  int sl = rem / KSPLIT;
  int kq = rem % KSPLIT;
  int n0 = sl * G2_BN;
  if (ti >= *ntiles) return;
  int e = tile_e[ti];
  int mbase = tile_mb[ti];
  int nrows = off[e + 1] - mbase; if (nrows > BM) nrows = BM;

  __shared__ u16 As[BM * BK];      // 16KB
  __shared__ u16 Bs[G2_BN * BK];   // 16KB

  int tid = threadIdx.x;
  int lane = tid & 63;
  int wid = tid >> 6;
  int wr = wid >> 1, wc = wid & 1;    // wave out 64 x 64
  int lrow = lane & 15, kgrp = lane >> 4;

  int srow = tid >> 3;
  int scol = ((tid & 7) ^ (srow & 7)) * 8;
  const u16* pA[4]; const u16* pB[4];
  const u16* w2base = w2b + (size_t)e * DIM * HID;
#pragma unroll
  for (int j = 0; j < 4; ++j) {
    int r = j * 32 + srow;
    int ra = r < nrows ? r : nrows - 1;
    pA[j] = hbuf + (size_t)(mbase + ra) * HID + scol;
    pB[j] = w2base + (size_t)(n0 + j * 32 + srow) * HID + scol;
  }

  f32x4 acc[4][4];
#pragma unroll
  for (int m = 0; m < 4; ++m)
#pragma unroll
    for (int n = 0; n < 4; ++n) acc[m][n] = (f32x4)0.f;

  int kt0 = kq * (NK2 / KSPLIT), kt1 = kt0 + NK2 / KSPLIT;
#pragma unroll 1
  for (int kt = kt0; kt < kt1; ++kt) {
    int kk = kt * BK;
#pragma unroll
    for (int j = 0; j < 4; ++j) {
      gload16(pA[j] + kk, &As[(j * 32 + wid * 8) * BK]);
      gload16(pB[j] + kk, &Bs[(j * 32 + wid * 8) * BK]);
    }
    __syncthreads();
#pragma unroll
    for (int ks = 0; ks < 2; ++ks) {
      int kc = ks * 32 + kgrp * 8;
      short8 a[4], bb[4];
#pragma unroll
      for (int m = 0; m < 4; ++m) a[m] = LDSWZ(As, wr * 64 + m * 16 + lrow, kc);
#pragma unroll
      for (int n = 0; n < 4; ++n) bb[n] = LDSWZ(Bs, wc * 64 + n * 16 + lrow, kc);
#pragma unroll
      for (int m = 0; m < 4; ++m)
#pragma unroll
        for (int n = 0; n < 4; ++n)
          acc[m][n] = __builtin_amdgcn_mfma_f32_16x16x32_bf16(a[m], bb[n], acc[m][n], 0, 0, 0);
    }
    __syncthreads();
  }

#pragma unroll
  for (int m = 0; m < 4; ++m) {
#pragma unroll
    for (int r = 0; r < 4; ++r) {
      int rowt = wr * 64 + m * 16 + kgrp * 4 + r;
      if (rowt < nrows) {
        int slot = mbase + rowt;
        int tok = pair_tok[slot];
        float w = pair_w[slot];
        float* orow = out + (size_t)tok * DIM;
#pragma unroll
        for (int n = 0; n < 4; ++n)
          atomicAdd(&orow[n0 + wc * 64 + n * 16 + lrow], acc[m][n][r] * w);
      }
    }
  }
}

extern "C" void kernel_launch(void* const* d_in, const int* in_sizes, int n_in,
                              void* d_out, int out_size, void* d_ws, size_t ws_size,
                              hipStream_t stream) {
  const float* x  = (const float*)d_in[0];
  const float* gw = (const float*)d_in[1];
  const float* w1 = (const float*)d_in[2];
  const float* w3 = (const float*)d_in[3];
  const float* w2 = (const float*)d_in[4];
  float* out = (float*)d_out;

  char* base = (char*)d_ws;
  size_t o = 0;
  auto alloc = [&](size_t bytes) {
    void* r = base + o;
    o = (o + bytes + 255) & ~(size_t)255;
    return r;
  };
  u16* xb      = (u16*)alloc((size_t)NTOK * DIM * 2);
  u16* w1b     = (u16*)alloc((size_t)NEXP * HID * DIM * 2);
  u16* w3b     = (u16*)alloc((size_t)NEXP * HID * DIM * 2);
  u16* w2b     = (u16*)alloc((size_t)NEXP * DIM * HID * 2);
  u16* hbuf    = (u16*)alloc((size_t)NPAIR * HID * 2);
  int* pair_tok = (int*)alloc((size_t)NPAIR * 4);
  float* pair_w = (float*)alloc((size_t)NPAIR * 4);
  int* tok_e    = (int*)alloc((size_t)NTOK * 2 * 4);
  float* tok_w  = (float*)alloc((size_t)NTOK * 2 * 4);
  int* cnt      = (int*)alloc(NEXP * 4);
  int* eoff     = (int*)alloc((NEXP + 1) * 4);
  int* fill     = (int*)alloc(NEXP * 4);
  int* tle      = (int*)alloc(MAXT * 4);
  int* tlmb     = (int*)alloc(MAXT * 4);
  int* ntiles   = (int*)alloc(4);

  hipMemsetAsync(d_out, 0, (size_t)out_size * sizeof(float), stream);
  hipMemsetAsync(cnt, 0, NEXP * sizeof(int), stream);

  router_kernel<<<NTOK, 64, 0, stream>>>(x, gw, cnt, tok_e, tok_w, xb);
  cvt3_kernel<<<2048, 256, 0, stream>>>(w1, w3, w2, w1b, w3b, w2b, NEXP * HID * DIM);
  prefix_kernel<<<1, 64, 0, stream>>>(cnt, eoff, fill, tle, tlmb, ntiles);
  scatter_kernel<<<NTOK / 256, 256, 0, stream>>>(tok_e, tok_w, eoff, fill,
                                                 pair_tok, pair_w);

  gemm1_kernel<<<G1_NWG, 256, 0, stream>>>(
      xb, w1b, w3b, hbuf, eoff, pair_tok, tle, tlmb, ntiles);
  gemm2_kernel<<<G2_NWG, 256, 0, stream>>>(
      hbuf, w2b, out, eoff, pair_tok, pair_w, tle, tlmb, ntiles);
}

// Round 15
// 712.178 us; speedup vs baseline: 1.0585x; 1.0585x over previous
//
#include <hip/hip_runtime.h>
#include <hip/hip_bf16.h>

// Problem constants (from reference)
#define NTOK 8192      // B*T = 4*2048
#define DIM 1024
#define NEXP 8
#define HID 2816
#define NPAIR (NTOK * 2)   // TOP_K = 2

#define BK 64
#define BM 128                 // shared m-tile worklist for both gemms
#define G1_BN 64               // h-cols per block (fused w1+w3)
#define G2_BN 128
#define MAXT 136               // >= ceil(NPAIR/128) + NEXP - 1 = 135
#define G1_NSL (HID / G1_BN)   // 44
#define G2_NSL (DIM / G2_BN)   // 8
#define G1_NWG (MAXT * G1_NSL) // 5984 (div by 8)
#define G2_NWG (MAXT * G2_NSL) // 1088 (div by 8)
#define NK1 (DIM / BK)         // 16
#define NK2 (HID / BK)         // 44

typedef unsigned short u16;
typedef __attribute__((ext_vector_type(8))) short short8;
typedef __attribute__((ext_vector_type(4))) float f32x4;

// T2 swizzled LDS read: logical (row, kc-u16) -> 16B-slot XOR by row&7.
// Plain C++ load: compiler emits fine-grained lgkmcnt interleaved with MFMAs.
#define LDSWZ(arr, r, kc) \
  (*(const short8*)&arr[(r) * BK + ((kc) ^ (((r) & 7) << 3))])

static __device__ __forceinline__ u16 f2bf(float f) {
  union { float f; unsigned u; } v; v.f = f;
  unsigned r = v.u + 0x7fff + ((v.u >> 16) & 1);  // RTNE
  return (u16)(r >> 16);
}

// async global->LDS, 16B/lane; LDS dest = wave-uniform base + lane*16B
static __device__ __forceinline__ void gload16(const void* g, void* l) {
  __builtin_amdgcn_global_load_lds(
      (const __attribute__((address_space(1))) unsigned*)(g),
      (__attribute__((address_space(3))) unsigned*)(l), 16, 0, 0);
}

// ---------------- fp32 -> bf16 conversion of the 3 weight tensors ----------
__global__ void cvt3_kernel(const float* __restrict__ s0, const float* __restrict__ s1,
                            const float* __restrict__ s2, u16* __restrict__ d0,
                            u16* __restrict__ d1, u16* __restrict__ d2, int n) {
  int stride = gridDim.x * blockDim.x;
  for (int i = blockIdx.x * blockDim.x + threadIdx.x; i * 4 < n; i += stride) {
    float4 a = *reinterpret_cast<const float4*>(s0 + (size_t)i * 4);
    float4 b = *reinterpret_cast<const float4*>(s1 + (size_t)i * 4);
    float4 c = *reinterpret_cast<const float4*>(s2 + (size_t)i * 4);
    ushort4 oa, ob, oc;
    oa.x = f2bf(a.x); oa.y = f2bf(a.y); oa.z = f2bf(a.z); oa.w = f2bf(a.w);
    ob.x = f2bf(b.x); ob.y = f2bf(b.y); ob.z = f2bf(b.z); ob.w = f2bf(b.w);
    oc.x = f2bf(c.x); oc.y = f2bf(c.y); oc.z = f2bf(c.z); oc.w = f2bf(c.w);
    *reinterpret_cast<ushort4*>(d0 + (size_t)i * 4) = oa;
    *reinterpret_cast<ushort4*>(d1 + (size_t)i * 4) = ob;
    *reinterpret_cast<ushort4*>(d2 + (size_t)i * 4) = oc;
  }
}

// ---------------- router (fused with x -> bf16 conversion) ------------------
__global__ void router_kernel(const float* __restrict__ x, const float* __restrict__ gw,
                              int* __restrict__ cnt, int* __restrict__ tok_e,
                              float* __restrict__ tok_w, u16* __restrict__ xb) {
  int t = blockIdx.x;
  int lane = threadIdx.x;  // 64 = 1 wave
  const float* xr = x + (size_t)t * DIM;
  u16* xbr = xb + (size_t)t * DIM;
  float acc[NEXP];
#pragma unroll
  for (int e = 0; e < NEXP; ++e) acc[e] = 0.f;
  for (int d = lane * 4; d < DIM; d += 256) {
    float4 v = *reinterpret_cast<const float4*>(xr + d);
    ushort4 o;
    o.x = f2bf(v.x); o.y = f2bf(v.y); o.z = f2bf(v.z); o.w = f2bf(v.w);
    *reinterpret_cast<ushort4*>(xbr + d) = o;
#pragma unroll
    for (int e = 0; e < NEXP; ++e) {
      const float* g = gw + e * DIM + d;
      acc[e] += v.x * g[0] + v.y * g[1] + v.z * g[2] + v.w * g[3];
    }
  }
#pragma unroll
  for (int e = 0; e < NEXP; ++e) {
#pragma unroll
    for (int o = 32; o > 0; o >>= 1) acc[e] += __shfl_xor(acc[e], o);
  }
  if (lane == 0) {
    float m = acc[0];
#pragma unroll
    for (int e = 1; e < NEXP; ++e) m = fmaxf(m, acc[e]);
    float p[NEXP];
#pragma unroll
    for (int e = 0; e < NEXP; ++e) p[e] = __expf(acc[e] - m);
    int e0 = 0; float b0 = p[0];
#pragma unroll
    for (int e = 1; e < NEXP; ++e) if (p[e] > b0) { e0 = e; b0 = p[e]; }
    int e1 = -1; float b1 = -1.f;
#pragma unroll
    for (int e = 0; e < NEXP; ++e) if (e != e0 && p[e] > b1) { e1 = e; b1 = p[e]; }
    float inv = 1.f / (b0 + b1);
    atomicAdd(&cnt[e0], 1);
    atomicAdd(&cnt[e1], 1);
    tok_e[2 * t] = e0; tok_e[2 * t + 1] = e1;
    tok_w[2 * t] = b0 * inv; tok_w[2 * t + 1] = b1 * inv;
  }
}

// ------- prefix + flat m-tile worklist (BM=128, shared by both gemms) ------
__global__ void prefix_kernel(const int* __restrict__ cnt, int* __restrict__ off,
                              int* __restrict__ fill,
                              int* __restrict__ tle, int* __restrict__ tlmb,
                              int* __restrict__ ntiles) {
  if (threadIdx.x == 0 && blockIdx.x == 0) {
    int s = 0, nt = 0;
    for (int e = 0; e < NEXP; ++e) {
      off[e] = s;
      for (int mb = 0; mb < cnt[e]; mb += BM) { tle[nt] = e; tlmb[nt] = s + mb; ++nt; }
      s += cnt[e]; fill[e] = 0;
    }
    off[NEXP] = s;
    *ntiles = nt;
  }
}

// ---------------- scatter --------------------------------------------------
__global__ void scatter_kernel(const int* __restrict__ tok_e, const float* __restrict__ tok_w,
                               const int* __restrict__ off, int* __restrict__ fill,
                               int* __restrict__ pair_tok, float* __restrict__ pair_w,
                               int* __restrict__ t2s) {
  int t = blockIdx.x * blockDim.x + threadIdx.x;
  if (t >= NTOK) return;
#pragma unroll
  for (int k = 0; k < 2; ++k) {
    int e = tok_e[2 * t + k];
    int slot = off[e] + atomicAdd(&fill[e], 1);
    pair_tok[slot] = t;
    pair_w[slot] = tok_w[2 * t + k];
    t2s[2 * t + k] = slot;
  }
}

// ---------------- GEMM1: h = silu(x @ w1^T) * (x @ w3^T) -------------------
// m97 structure: 128x64 fused tile, 4 waves (2x2), single-buffer 32KB LDS,
// 2-sync K-loop (3 blocks/CU -> implicit cross-block overlap). T2 swizzle.
__launch_bounds__(256, 3)
__global__ void gemm1_kernel(const u16* __restrict__ xb, const u16* __restrict__ w1b,
                             const u16* __restrict__ w3b, u16* __restrict__ hbuf,
                             const int* __restrict__ off, const int* __restrict__ pair_tok,
                             const int* __restrict__ tile_e, const int* __restrict__ tile_mb,
                             const int* __restrict__ ntiles) {
  int bid = blockIdx.x;
  int swz = (bid & 7) * (G1_NWG / 8) + (bid >> 3);   // bijective: G1_NWG%8==0
  int ti = swz / G1_NSL;                              // A-major for L2 reuse
  int n0 = (swz % G1_NSL) * G1_BN;
  if (ti >= *ntiles) return;
  int e = tile_e[ti];
  int mbase = tile_mb[ti];
  int nrows = off[e + 1] - mbase; if (nrows > BM) nrows = BM;

  __shared__ u16 As[BM * BK];      // 16KB, single buffer
  __shared__ u16 B1s[G1_BN * BK];  // 8KB
  __shared__ u16 B3s[G1_BN * BK];  // 8KB

  int tid = threadIdx.x;
  int lane = tid & 63;
  int wid = tid >> 6;
  int wr = wid >> 1, wc = wid & 1;     // 2(M) x 2(N); wave out 64 x 32 (x2 mats)
  int lrow = lane & 15, kgrp = lane >> 4;

  int srow = tid >> 3;                              // 0..31
  int scol = ((tid & 7) ^ (srow & 7)) * 8;          // rule #21: swz on source
  const u16* pA[4]; const u16* pB1[2]; const u16* pB3[2];
  const u16* w1base = w1b + (size_t)e * HID * DIM;
  const u16* w3base = w3b + (size_t)e * HID * DIM;
#pragma unroll
  for (int j = 0; j < 4; ++j) {
    int r = j * 32 + srow;
    int ra = r < nrows ? r : nrows - 1;             // clamp ragged tile
    pA[j] = xb + (size_t)pair_tok[mbase + ra] * DIM + scol;
  }
#pragma unroll
  for (int j = 0; j < 2; ++j) {
    int r = j * 32 + srow;
    pB1[j] = w1base + (size_t)(n0 + r) * DIM + scol;
    pB3[j] = w3base + (size_t)(n0 + r) * DIM + scol;
  }

  f32x4 acc1[4][2], acc3[4][2];
#pragma unroll
  for (int m = 0; m < 4; ++m)
#pragma unroll
    for (int n = 0; n < 2; ++n) { acc1[m][n] = (f32x4)0.f; acc3[m][n] = (f32x4)0.f; }

#pragma unroll 1
  for (int kt = 0; kt < NK1; ++kt) {
    int kk = kt * BK;
    // stage: 8 gload16 per wave (As 4, B1s 2, B3s 2); dest linear per wave
#pragma unroll
    for (int j = 0; j < 4; ++j)
      gload16(pA[j] + kk, &As[(j * 32 + wid * 8) * BK]);
#pragma unroll
    for (int j = 0; j < 2; ++j) {
      gload16(pB1[j] + kk, &B1s[(j * 32 + wid * 8) * BK]);
      gload16(pB3[j] + kk, &B3s[(j * 32 + wid * 8) * BK]);
    }
    __syncthreads();   // drains vmcnt(0): whole tile in LDS
#pragma unroll
    for (int ks = 0; ks < 2; ++ks) {
      int kc = ks * 32 + kgrp * 8;
      short8 a[4], b1[2], b3[2];
#pragma unroll
      for (int m = 0; m < 4; ++m) a[m] = LDSWZ(As, wr * 64 + m * 16 + lrow, kc);
#pragma unroll
      for (int n = 0; n < 2; ++n) {
        b1[n] = LDSWZ(B1s, wc * 32 + n * 16 + lrow, kc);
        b3[n] = LDSWZ(B3s, wc * 32 + n * 16 + lrow, kc);
      }
#pragma unroll
      for (int m = 0; m < 4; ++m)
#pragma unroll
        for (int n = 0; n < 2; ++n) {
          acc1[m][n] = __builtin_amdgcn_mfma_f32_16x16x32_bf16(a[m], b1[n], acc1[m][n], 0, 0, 0);
          acc3[m][n] = __builtin_amdgcn_mfma_f32_16x16x32_bf16(a[m], b3[n], acc3[m][n], 0, 0, 0);
        }
    }
    __syncthreads();   // all reads complete -> next stage may overwrite
  }

  // epilogue: silu(acc1)*acc3 -> bf16 h
#pragma unroll
  for (int m = 0; m < 4; ++m)
#pragma unroll
    for (int n = 0; n < 2; ++n)
#pragma unroll
      for (int r = 0; r < 4; ++r) {
        int rowt = wr * 64 + m * 16 + kgrp * 4 + r;   // C/D: row=(lane>>4)*4+r, col=lane&15
        if (rowt < nrows) {
          float v1 = acc1[m][n][r], v3 = acc3[m][n][r];
          float hv = v1 / (1.f + __expf(-v1)) * v3;
          hbuf[(size_t)(mbase + rowt) * HID + (n0 + wc * 32 + n * 16 + lrow)] = f2bf(hv);
        }
      }
}

// ---------------- GEMM2: y2[slot] = (h @ w2^T) * pair_w --------------------
// m97 structure: 128x128 tile, 4 waves (2x2), wave 64x64, single-buffer 32KB.
__launch_bounds__(256, 3)
__global__ void gemm2_kernel(const u16* __restrict__ hbuf, const u16* __restrict__ w2b,
                             float* __restrict__ y2, const int* __restrict__ off,
                             const float* __restrict__ pair_w,
                             const int* __restrict__ tile_e, const int* __restrict__ tile_mb,
                             const int* __restrict__ ntiles) {
  int bid = blockIdx.x;
  int swz = (bid & 7) * (G2_NWG / 8) + (bid >> 3);
  int ti = swz / G2_NSL;
  int n0 = (swz % G2_NSL) * G2_BN;
  if (ti >= *ntiles) return;
  int e = tile_e[ti];
  int mbase = tile_mb[ti];
  int nrows = off[e + 1] - mbase; if (nrows > BM) nrows = BM;

  __shared__ u16 As[BM * BK];      // 16KB
  __shared__ u16 Bs[G2_BN * BK];   // 16KB

  int tid = threadIdx.x;
  int lane = tid & 63;
  int wid = tid >> 6;
  int wr = wid >> 1, wc = wid & 1;    // wave out 64 x 64
  int lrow = lane & 15, kgrp = lane >> 4;

  int srow = tid >> 3;
  int scol = ((tid & 7) ^ (srow & 7)) * 8;
  const u16* pA[4]; const u16* pB[4];
  const u16* w2base = w2b + (size_t)e * DIM * HID;
#pragma unroll
  for (int j = 0; j < 4; ++j) {
    int r = j * 32 + srow;
    int ra = r < nrows ? r : nrows - 1;
    pA[j] = hbuf + (size_t)(mbase + ra) * HID + scol;
    pB[j] = w2base + (size_t)(n0 + j * 32 + srow) * HID + scol;
  }

  f32x4 acc[4][4];
#pragma unroll
  for (int m = 0; m < 4; ++m)
#pragma unroll
    for (int n = 0; n < 4; ++n) acc[m][n] = (f32x4)0.f;

#pragma unroll 1
  for (int kt = 0; kt < NK2; ++kt) {
    int kk = kt * BK;
#pragma unroll
    for (int j = 0; j < 4; ++j) {
      gload16(pA[j] + kk, &As[(j * 32 + wid * 8) * BK]);
      gload16(pB[j] + kk, &Bs[(j * 32 + wid * 8) * BK]);
    }
    __syncthreads();
#pragma unroll
    for (int ks = 0; ks < 2; ++ks) {
      int kc = ks * 32 + kgrp * 8;
      short8 a[4], bb[4];
#pragma unroll
      for (int m = 0; m < 4; ++m) a[m] = LDSWZ(As, wr * 64 + m * 16 + lrow, kc);
#pragma unroll
      for (int n = 0; n < 4; ++n) bb[n] = LDSWZ(Bs, wc * 64 + n * 16 + lrow, kc);
#pragma unroll
      for (int m = 0; m < 4; ++m)
#pragma unroll
        for (int n = 0; n < 4; ++n)
          acc[m][n] = __builtin_amdgcn_mfma_f32_16x16x32_bf16(a[m], bb[n], acc[m][n], 0, 0, 0);
    }
    __syncthreads();
  }

#pragma unroll
  for (int m = 0; m < 4; ++m) {
#pragma unroll
    for (int r = 0; r < 4; ++r) {
      int rowt = wr * 64 + m * 16 + kgrp * 4 + r;
      if (rowt < nrows) {
        int slot = mbase + rowt;
        float w = pair_w[slot];
#pragma unroll
        for (int n = 0; n < 4; ++n)
          y2[(size_t)slot * DIM + (n0 + wc * 64 + n * 16 + lrow)] = acc[m][n][r] * w;
      }
    }
  }
}

// ---------------- combine: out[t] = y2[slot0] + y2[slot1] ------------------
__global__ void combine_kernel(const float* __restrict__ y2, const int* __restrict__ t2s,
                               float* __restrict__ out) {
  int t = blockIdx.x;
  int c = threadIdx.x;
  int s0 = t2s[2 * t], s1 = t2s[2 * t + 1];
  float4 a = *(const float4*)(y2 + (size_t)s0 * DIM + c * 4);
  float4 b = *(const float4*)(y2 + (size_t)s1 * DIM + c * 4);
  float4 o;
  o.x = a.x + b.x; o.y = a.y + b.y; o.z = a.z + b.z; o.w = a.w + b.w;
  *(float4*)(out + (size_t)t * DIM + c * 4) = o;
}

extern "C" void kernel_launch(void* const* d_in, const int* in_sizes, int n_in,
                              void* d_out, int out_size, void* d_ws, size_t ws_size,
                              hipStream_t stream) {
  const float* x  = (const float*)d_in[0];
  const float* gw = (const float*)d_in[1];
  const float* w1 = (const float*)d_in[2];
  const float* w3 = (const float*)d_in[3];
  const float* w2 = (const float*)d_in[4];
  float* out = (float*)d_out;

  char* base = (char*)d_ws;
  size_t o = 0;
  auto alloc = [&](size_t bytes) {
    void* r = base + o;
    o = (o + bytes + 255) & ~(size_t)255;
    return r;
  };
  u16* xb      = (u16*)alloc((size_t)NTOK * DIM * 2);
  u16* w1b     = (u16*)alloc((size_t)NEXP * HID * DIM * 2);
  u16* w3b     = (u16*)alloc((size_t)NEXP * HID * DIM * 2);
  u16* w2b     = (u16*)alloc((size_t)NEXP * DIM * HID * 2);
  u16* hbuf    = (u16*)alloc((size_t)NPAIR * HID * 2);
  int* pair_tok = (int*)alloc((size_t)NPAIR * 4);
  float* pair_w = (float*)alloc((size_t)NPAIR * 4);
  int* tok_e    = (int*)alloc((size_t)NTOK * 2 * 4);
  float* tok_w  = (float*)alloc((size_t)NTOK * 2 * 4);
  int* t2s      = (int*)alloc((size_t)NTOK * 2 * 4);
  int* cnt      = (int*)alloc(NEXP * 4);
  int* eoff     = (int*)alloc((NEXP + 1) * 4);
  int* fill     = (int*)alloc(NEXP * 4);
  int* tle      = (int*)alloc(MAXT * 4);
  int* tlmb     = (int*)alloc(MAXT * 4);
  int* ntiles   = (int*)alloc(4);
  float* y2     = (float*)w1b;   // 67MB partials alias w1b+w3b (92MB, dead post-gemm1)

  hipMemsetAsync(cnt, 0, NEXP * sizeof(int), stream);

  router_kernel<<<NTOK, 64, 0, stream>>>(x, gw, cnt, tok_e, tok_w, xb);
  cvt3_kernel<<<2048, 256, 0, stream>>>(w1, w3, w2, w1b, w3b, w2b, NEXP * HID * DIM);
  prefix_kernel<<<1, 64, 0, stream>>>(cnt, eoff, fill, tle, tlmb, ntiles);
  scatter_kernel<<<NTOK / 256, 256, 0, stream>>>(tok_e, tok_w, eoff, fill,
                                                 pair_tok, pair_w, t2s);

  gemm1_kernel<<<G1_NWG, 256, 0, stream>>>(
      xb, w1b, w3b, hbuf, eoff, pair_tok, tle, tlmb, ntiles);
  gemm2_kernel<<<G2_NWG, 256, 0, stream>>>(
      hbuf, w2b, y2, eoff, pair_w, tle, tlmb, ntiles);
  combine_kernel<<<NTOK, 256, 0, stream>>>(y2, t2s, out);
}